// Round 2
// baseline (215.479 us; speedup 1.0000x reference)
//
#include <hip/hip_runtime.h>
#include <hip/hip_bf16.h>
#include <math.h>

#define B_   4
#define C_   256
#define H_   96
#define W_   96
#define HW_  (H_ * W_)
#define G_   4
#define CG_  64
#define K_   9
#define PW_  98                            // padded width/height (1-px halo)
#define PROW_ (PW_ * C_)                   // padded row pitch in elems

typedef __bf16  bf16x8 __attribute__((ext_vector_type(8)));
typedef float   f32x4  __attribute__((ext_vector_type(4)));

// ---------------------------------------------------------------------------
// prep:
//  aOW: offset-conv weights, MFMA A order, M padded 18->32:
//    m = mt*16 + (lane&15) (out chan, 0 if >=18); k = ks*32+(lane>>4)*8+j (c)
//  aW: deform weights bf16, MFMA A order:
//    c = ks*32+(lane>>4)*8+j ; co = half*32+ct*16+(lane&15)
// ---------------------------------------------------------------------------
__global__ __launch_bounds__(256) void prep_kernel(
    const float* __restrict__ ow, const float* __restrict__ wt,
    __hip_bfloat16* __restrict__ aOW, __hip_bfloat16* __restrict__ aW)
{
    int idx = blockIdx.x * 256 + threadIdx.x;
    if (idx < 73728) {
        int j    = idx & 7;
        int r    = idx >> 3;
        int lane = r & 63;  r >>= 6;
        int mt   = r & 1;   r >>= 1;
        int ks   = r & 7;   r >>= 3;
        int tap  = r;                     // 0..8
        int m = mt * 16 + (lane & 15);
        int c = ks * 32 + (lane >> 4) * 8 + j;
        float v = (m < 18) ? ow[(m * 256 + c) * 9 + tap] : 0.f;
        aOW[idx] = __float2bfloat16(v);
    }
    if (idx < 147456) {
        int j    = idx & 7;
        int r    = idx >> 3;
        int lane = r & 63;  r >>= 6;
        int ct   = r & 1;   r >>= 1;
        int half = r & 1;   r >>= 1;
        int ks   = r & 1;   r >>= 1;
        int tap  = r % 9;
        int g    = r / 9;
        int c  = ks * 32 + (lane >> 4) * 8 + j;
        int co = half * 32 + ct * 16 + (lane & 15);
        float v = wt[(((g * CG_ + co) * CG_ + c) * 9) + tap];
        aW[idx] = __float2bfloat16(v);
    }
}

// ---------------------------------------------------------------------------
// transpose x (NCHW fp32) -> xtp (padded NHWC bf16, [b][98][98][256], halo=0).
// c-split in half -> 768 blocks (3/CU exactly), 25.5KB LDS tile.
// ---------------------------------------------------------------------------
__global__ __launch_bounds__(256) void transpose_kernel(
    const float* __restrict__ x, __hip_bfloat16* __restrict__ xtp)
{
    int blk = blockIdx.x;                 // 0..767 = (b*96 + h)*2 + chalf
    int ch  = blk & 1;
    int bh  = blk >> 1;
    int b = bh / H_, h = bh - b * H_;
    int t = threadIdx.x;
    __shared__ __align__(16) __hip_bfloat16 tile[96 * 136];   // [w][128c + 8 pad]
    const float* xb = x + (size_t)b * C_ * HW_ + (size_t)(ch * 128) * HW_ + h * W_;
    for (int r = 0; r < 48; ++r) {
        int e = r * 256 + t;              // 0..12287 = c*96 + w  (c in 0..127)
        int c = e / 96, w = e - c * 96;
        tile[w * 136 + c] = __float2bfloat16(xb[c * HW_ + w]);
    }
    __syncthreads();
    __hip_bfloat16* ob = xtp + ((size_t)(b * PW_ + h + 1) * PW_ + 1) * C_ + ch * 128;
#pragma unroll
    for (int i = 0; i < 6; ++i) {
        int sIdx = i * 256 + t;           // 0..1535
        int px = sIdx >> 4, seg = sIdx & 15;
        *(bf16x8*)(ob + px * 256 + seg * 8) =
            *(const bf16x8*)(&tile[px * 136 + seg * 8]);
    }
    bf16x8 z = {};
    if (t < 32) {                         // column halos (this c-half)
        int side = t >> 4, i = t & 15;
        *(bf16x8*)(xtp + ((size_t)(b * PW_ + h + 1) * PW_ + side * 97) * C_
                   + ch * 128 + i * 8) = z;
    }
    if (h == 0 || h == 95) {              // top/bottom halo rows, split by chalf
        int row = (h == 0) ? 0 : 97;
        __hip_bfloat16* rb = xtp + (size_t)(b * PW_ + row) * PROW_;
        for (int i = 0; i < 7; ++i) {
            int idx = i * 256 + t;        // 0..1567 of this half
            if (idx < 1568) *(bf16x8*)(rb + (ch * 1568 + idx) * 8) = z;
        }
    }
}

// ---------------------------------------------------------------------------
// offset conv via MFMA, K-split 2 halves + A staged in LDS (double-buffered,
// 1 barrier/tap). w-split in half -> 768 blocks x 384 thr (6 waves =
// 3 w-tiles x 2 k-halves) = 3 blocks/CU exactly.
// ---------------------------------------------------------------------------
__global__ __launch_bounds__(384) void offset_conv_kernel(
    const __hip_bfloat16* __restrict__ xtp, const __hip_bfloat16* __restrict__ aOW,
    const float* __restrict__ bias, __hip_bfloat16* __restrict__ off2)
{
    int blk = blockIdx.x;                 // 0..767
    int xcd = blk & 7;
    int s   = blk >> 3;                   // 0..95
    int unit = xcd * 96 + s;              // XCD-chunked: neighbors share rows
    int bh   = unit >> 1;
    int whalf = unit & 1;
    int b   = bh / H_, h = bh % H_;
    int t = threadIdx.x, lane = t & 63;
    int ww = __builtin_amdgcn_readfirstlane(t >> 6);  // 0..5
    int nt = ww % 3;                      // w tile
    int kh = ww / 3;                      // k half
    int w0 = whalf * 48 + nt * 16;
    int ml = lane & 15, kq = lane >> 4;

    __shared__ __align__(16) __hip_bfloat16 aS[2][8192];   // per-tap A slice
    __shared__ __align__(16) f32x4 red[3 * 64 * 2];

    auto stage = [&](int tap, int p) {
        const bf16x8* src = (const bf16x8*)(aOW + tap * 8192);
        bf16x8* dst = (bf16x8*)aS[p];
        for (int i = t; i < 1024; i += 384) dst[i] = src[i];
    };

    f32x4 acc0 = {}, acc1 = {};
    const __hip_bfloat16* xb = xtp + (size_t)b * (PW_ * PROW_);

    stage(0, 0);
    __syncthreads();
    for (int tap = 0; tap < 9; ++tap) {
        if (tap < 8) stage(tap + 1, (tap + 1) & 1);   // loads issue early
        int ky = tap / 3, kx = tap - ky * 3;
        const __hip_bfloat16* brow =
            xb + ((h + ky) * PW_ + (w0 + ml + kx)) * C_ + kh * 128 + kq * 8;
        const __hip_bfloat16* arow = aS[tap & 1] + kh * 4096 + lane * 8;
#pragma unroll
        for (int ks = 0; ks < 4; ++ks) {
            bf16x8 bf = *(const bf16x8*)(brow + ks * 32);
            bf16x8 a0 = *(const bf16x8*)(arow + ks * 1024);
            bf16x8 a1 = *(const bf16x8*)(arow + ks * 1024 + 512);
            acc0 = __builtin_amdgcn_mfma_f32_16x16x32_bf16(a0, bf, acc0, 0, 0, 0);
            acc1 = __builtin_amdgcn_mfma_f32_16x16x32_bf16(a1, bf, acc1, 0, 0, 0);
        }
        __syncthreads();
    }

    // cross-half reduction in LDS
    if (kh == 1) {
        red[(nt * 64 + lane) * 2 + 0] = acc0;
        red[(nt * 64 + lane) * 2 + 1] = acc1;
    }
    __syncthreads();
    if (kh == 0) {
        acc0 += red[(nt * 64 + lane) * 2 + 0];
        acc1 += red[(nt * 64 + lane) * 2 + 1];
        // C/D: col=lane&15 -> w, row=kq*4+r -> out channel j
        int w = w0 + ml;
#pragma unroll
        for (int r = 0; r < 4; ++r) {
            int j0 = kq * 4 + r;
            off2[((size_t)(b * 9 + (j0 >> 1)) * HW_ + h * W_ + w) * 2 + (j0 & 1)] =
                __float2bfloat16(acc0[r] + bias[j0]);
            int j1 = 16 + kq * 4 + r;
            if (j1 < 18)
                off2[((size_t)(b * 9 + (j1 >> 1)) * HW_ + h * W_ + w) * 2 + (j1 & 1)] =
                    __float2bfloat16(acc1[r] + bias[j1]);
        }
    }
}

// ---------------------------------------------------------------------------
// deform conv via MFMA — v3: BARRIER-FREE, LDS-FREE, wave-autonomous.
// Insight: the MFMA B-fragment layout is B[k=ks*32+(lane>>4)*8+e][n=lane&15],
// so each lane can SAMPLE exactly the fragment element it feeds to the MFMA:
// lane (wq=lane>>4, wn=lane&15) samples channels wq*8..+7 (+ks*32) at
// w = wt*16+wn. One wave owns a full (16 w x 64 co) output tile: gathers its
// own B-frags in-register, loads A-frags from L2-hot aW, 8 MFMA/tap.
// No sS tile, no __syncthreads, no cross-wave coupling -> waves free-run and
// plain TLP hides gather latency (v1/v2 were phase-locked by 9 barriers/block:
// MfmaUtil 7.5%, ~50% stall; v2's reg-pipeline across the barrier spilled to
// scratch: +46MB HBM traffic). Total gathers/VALU/MFMA per (b,g,h) unchanged;
// offset-math redundancy drops 8x->4x; 1.33M LDS bank conflicts eliminated.
// Accumulation order (tap-major, ks-ascending, bf16-rounded samples) is
// bit-identical to v1.
// ---------------------------------------------------------------------------
__global__ __launch_bounds__(256, 4) void deform_kernel(
    const __hip_bfloat16* __restrict__ xtp, const __hip_bfloat16* __restrict__ off2,
    const __hip_bfloat16* __restrict__ aW, float* __restrict__ out)
{
    int blk = blockIdx.x;                 // 0..2303
    int xcd = blk & 7;
    int unit = xcd * 288 + (blk >> 3);    // XCD-chunked: contiguous task range
    int wv  = __builtin_amdgcn_readfirstlane(threadIdx.x >> 6); // 0..3
    int task = unit * 4 + wv;             // 0..9215 = ((b*4+g)*96+h)*6 + wt
    int wt  = task % 6;
    int r0  = task / 6;
    int h   = r0 % H_;
    int bg  = r0 / H_;
    int g   = bg & 3;
    int b   = bg >> 2;
    int lane = threadIdx.x & 63;
    int wq = lane >> 4;                   // c-quad (8 channels) / C-row quad
    int wn = lane & 15;                   // B col = w within tile
    int w  = wt * 16 + wn;

    // interior origin: padded (1,1) == image (0,0); this lane's channel slice
    const __hip_bfloat16* xb =
        xtp + ((size_t)b * (PW_ * PW_) + PW_ + 1) * C_ + g * CG_ + wq * 8;
    const __hip_bfloat162* offp =
        (const __hip_bfloat162*)off2 + (size_t)(b * 9) * HW_ + h * W_ + w;
    const __hip_bfloat16* aWg = aW + (size_t)(g * 9) * 4096 + lane * 8;

    f32x4 acc[4] = {};                    // [hc = half*2+ct] -> co = hc*16+wq*4+r

    __hip_bfloat162 pr[9];                // all tap offsets up front (kills the
#pragma unroll                            // off->addr serial chain)
    for (int k = 0; k < 9; ++k) pr[k] = offp[k * HW_];

#pragma unroll
    for (int k = 0; k < 9; ++k) {
        int ky = k / 3, kx = k - ky * 3;
        float py = (float)(h + ky - 1) + __bfloat162float(pr[k].x);
        float px = (float)(w + kx - 1) + __bfloat162float(pr[k].y);
        bool valid = (py > -1.f) && (py < (float)H_) &&
                     (px > -1.f) && (px < (float)W_);
        float y0f = floorf(py), x0f = floorf(px);
        float ly = py - y0f, lx = px - x0f;
        int y0 = (int)y0f, x0 = (int)x0f;
        // valid => all 4 corners inside padded image.
        // invalid => base -> padded (0,0) halo corner, weights zeroed.
        int base = valid ? (y0 * PW_ + x0) * C_ : -(PW_ + 1) * C_;
        float wy1 = valid ? ly : 0.f;
        float wy0 = valid ? (1.f - ly) : 0.f;
        float mx0 = 1.f - lx;
        float bw00 = wy0 * mx0, bw01 = wy0 * lx;
        float bw10 = wy1 * mx0, bw11 = wy1 * lx;
        const __hip_bfloat16* p0 = xb + base;

        bf16x8 bfrag[2];
#pragma unroll
        for (int ks = 0; ks < 2; ++ks) {
            const __hip_bfloat16* pk = p0 + ks * 32;
            bf16x8 c00 = *(const bf16x8*)(pk);
            bf16x8 c01 = *(const bf16x8*)(pk + C_);
            bf16x8 c10 = *(const bf16x8*)(pk + PROW_);
            bf16x8 c11 = *(const bf16x8*)(pk + PROW_ + C_);
#pragma unroll
            for (int e = 0; e < 8; ++e) {
                float v = bw00 * (float)c00[e] + bw01 * (float)c01[e]
                        + bw10 * (float)c10[e] + bw11 * (float)c11[e];
                bfrag[ks][e] = (__bf16)v;
            }
        }

        const __hip_bfloat16* at = aWg + k * 4096;
#pragma unroll
        for (int ks = 0; ks < 2; ++ks)
#pragma unroll
            for (int hc = 0; hc < 4; ++hc) {
                bf16x8 af = *(const bf16x8*)(at + ks * 2048 + hc * 512);
                acc[hc] = __builtin_amdgcn_mfma_f32_16x16x32_bf16(
                              af, bfrag[ks], acc[hc], 0, 0, 0);
            }
    }

    // epilogue: C/D layout col=lane&15 (w), row=(lane>>4)*4+reg (co)
    float* ob = out + ((size_t)(b * C_ + g * CG_ + wq * 4)) * HW_ + h * W_ + w;
#pragma unroll
    for (int hc = 0; hc < 4; ++hc)
#pragma unroll
        for (int rr = 0; rr < 4; ++rr)
            __builtin_nontemporal_store(acc[hc][rr], ob + (hc * 16 + rr) * HW_);
}

// ---------------------------------------------------------------------------
extern "C" void kernel_launch(void* const* d_in, const int* in_sizes, int n_in,
                              void* d_out, int out_size, void* d_ws, size_t ws_size,
                              hipStream_t stream) {
    const float* x    = (const float*)d_in[0];
    const float* ow   = (const float*)d_in[1];   // offset_w (18,256,3,3)
    const float* obi  = (const float*)d_in[2];   // offset_b (18,)
    const float* wt   = (const float*)d_in[3];   // weight   (256,64,3,3)

    // ws: xtp bf16 padded (19.67MB) | off2 bf16 (1.33MB) | aW (0.29MB) | aOW (0.15MB)
    __hip_bfloat16* xtp  = (__hip_bfloat16*)d_ws;
    __hip_bfloat16* off2 = xtp + (size_t)B_ * PW_ * PW_ * C_;
    __hip_bfloat16* aW   = off2 + (size_t)B_ * 9 * HW_ * 2;
    __hip_bfloat16* aOW  = aW + 147456;

    prep_kernel<<<576, 256, 0, stream>>>(ow, wt, aOW, aW);
    transpose_kernel<<<B_ * H_ * 2, 256, 0, stream>>>(x, xtp);
    offset_conv_kernel<<<B_ * H_ * 2, 384, 0, stream>>>(xtp, aOW, obi, off2);
    deform_kernel<<<B_ * G_ * H_ * 6 / 4, 256, 0, stream>>>(xtp, off2, aW, (float*)d_out);
}

// Round 3
// 169.397 us; speedup vs baseline: 1.2720x; 1.2720x over previous
//
#include <hip/hip_runtime.h>
#include <hip/hip_bf16.h>
#include <math.h>

#define B_   4
#define C_   256
#define H_   96
#define W_   96
#define HW_  (H_ * W_)
#define G_   4
#define CG_  64
#define K_   9
#define PW_  98                            // padded width/height (1-px halo)
#define PROW_ (PW_ * C_)                   // padded row pitch in elems

typedef __bf16  bf16x8 __attribute__((ext_vector_type(8)));
typedef float   f32x4  __attribute__((ext_vector_type(4)));

// ---------------------------------------------------------------------------
// transpose+prep fused (prep is tiny; fusing removes one launch + bubble).
// prep part:
//  aOW: offset-conv weights, MFMA A order, M padded 18->32:
//    m = mt*16 + (lane&15) (out chan, 0 if >=18); k = ks*32+(lane>>4)*8+j (c)
//  aW: deform weights bf16, MFMA A order:
//    c = ks*32+(lane>>4)*8+j ; co = half*32+ct*16+(lane&15)
// transpose part: x (NCHW fp32) -> xtp (padded NHWC bf16 [b][98][98][256],
// halo=0). c-split in half -> 768 blocks (3/CU exactly), 25.5KB LDS tile.
// v4: global loads vectorized float4 (48 scalar dword -> 12 dwordx4 / thread).
// ---------------------------------------------------------------------------
__global__ __launch_bounds__(256) void transpose_prep_kernel(
    const float* __restrict__ x, const float* __restrict__ ow,
    const float* __restrict__ wt, __hip_bfloat16* __restrict__ xtp,
    __hip_bfloat16* __restrict__ aOW, __hip_bfloat16* __restrict__ aW)
{
    int t = threadIdx.x;
    int gid = blockIdx.x * 256 + t;       // 0..196607 (768 blocks)

    // ---- prep: offset-conv weights ----
    if (gid < 73728) {
        int j    = gid & 7;
        int r    = gid >> 3;
        int lane = r & 63;  r >>= 6;
        int mt   = r & 1;   r >>= 1;
        int ks   = r & 7;   r >>= 3;
        int tap  = r;                     // 0..8
        int m = mt * 16 + (lane & 15);
        int c = ks * 32 + (lane >> 4) * 8 + j;
        float v = (m < 18) ? ow[(m * 256 + c) * 9 + tap] : 0.f;
        aOW[gid] = __float2bfloat16(v);
    }
    // ---- prep: deform weights ----
    if (gid < 147456) {
        int j    = gid & 7;
        int r    = gid >> 3;
        int lane = r & 63;  r >>= 6;
        int ct   = r & 1;   r >>= 1;
        int half = r & 1;   r >>= 1;
        int ks   = r & 1;   r >>= 1;
        int tap  = r % 9;
        int g    = r / 9;
        int c  = ks * 32 + (lane >> 4) * 8 + j;
        int co = half * 32 + ct * 16 + (lane & 15);
        float v = wt[(((g * CG_ + co) * CG_ + c) * 9) + tap];
        aW[gid] = __float2bfloat16(v);
    }

    // ---- transpose ----
    int blk = blockIdx.x;                 // 0..767 = (b*96 + h)*2 + chalf
    int ch  = blk & 1;
    int bh  = blk >> 1;
    int b = bh / H_, h = bh - b * H_;
    __shared__ __align__(16) __hip_bfloat16 tile[96 * 136];   // [w][128c + 8 pad]
    const float* xb = x + (size_t)b * C_ * HW_ + (size_t)(ch * 128) * HW_ + h * W_;
#pragma unroll
    for (int r = 0; r < 12; ++r) {
        int e4 = r * 256 + t;             // 0..3071 float4 units (c*24 + w4)
        int c = e4 / 24, w4 = e4 - c * 24;
        float4 v = *(const float4*)(xb + (size_t)c * HW_ + w4 * 4);
        int base = (w4 * 4) * 136 + c;
        tile[base      ] = __float2bfloat16(v.x);
        tile[base + 136] = __float2bfloat16(v.y);
        tile[base + 272] = __float2bfloat16(v.z);
        tile[base + 408] = __float2bfloat16(v.w);
    }
    __syncthreads();
    __hip_bfloat16* ob = xtp + ((size_t)(b * PW_ + h + 1) * PW_ + 1) * C_ + ch * 128;
#pragma unroll
    for (int i = 0; i < 6; ++i) {
        int sIdx = i * 256 + t;           // 0..1535
        int px = sIdx >> 4, seg = sIdx & 15;
        *(bf16x8*)(ob + px * 256 + seg * 8) =
            *(const bf16x8*)(&tile[px * 136 + seg * 8]);
    }
    bf16x8 z = {};
    if (t < 32) {                         // column halos (this c-half)
        int side = t >> 4, i = t & 15;
        *(bf16x8*)(xtp + ((size_t)(b * PW_ + h + 1) * PW_ + side * 97) * C_
                   + ch * 128 + i * 8) = z;
    }
    if (h == 0 || h == 95) {              // top/bottom halo rows, split by chalf
        int row = (h == 0) ? 0 : 97;
        __hip_bfloat16* rb = xtp + (size_t)(b * PW_ + row) * PROW_;
        for (int i = 0; i < 7; ++i) {
            int idx = i * 256 + t;        // 0..1567 of this half
            if (idx < 1568) *(bf16x8*)(rb + (ch * 1568 + idx) * 8) = z;
        }
    }
}

// ---------------------------------------------------------------------------
// offset conv via MFMA, K-split 2 halves + A staged in LDS (double-buffered,
// 1 barrier/tap). w-split in half -> 768 blocks x 384 thr (6 waves =
// 3 w-tiles x 2 k-halves) = 3 blocks/CU exactly.
// ---------------------------------------------------------------------------
__global__ __launch_bounds__(384) void offset_conv_kernel(
    const __hip_bfloat16* __restrict__ xtp, const __hip_bfloat16* __restrict__ aOW,
    const float* __restrict__ bias, __hip_bfloat16* __restrict__ off2)
{
    int blk = blockIdx.x;                 // 0..767
    int xcd = blk & 7;
    int s   = blk >> 3;                   // 0..95
    int unit = xcd * 96 + s;              // XCD-chunked: neighbors share rows
    int bh   = unit >> 1;
    int whalf = unit & 1;
    int b   = bh / H_, h = bh % H_;
    int t = threadIdx.x, lane = t & 63;
    int ww = __builtin_amdgcn_readfirstlane(t >> 6);  // 0..5
    int nt = ww % 3;                      // w tile
    int kh = ww / 3;                      // k half
    int w0 = whalf * 48 + nt * 16;
    int ml = lane & 15, kq = lane >> 4;

    __shared__ __align__(16) __hip_bfloat16 aS[2][8192];   // per-tap A slice
    __shared__ __align__(16) f32x4 red[3 * 64 * 2];

    auto stage = [&](int tap, int p) {
        const bf16x8* src = (const bf16x8*)(aOW + tap * 8192);
        bf16x8* dst = (bf16x8*)aS[p];
        for (int i = t; i < 1024; i += 384) dst[i] = src[i];
    };

    f32x4 acc0 = {}, acc1 = {};
    const __hip_bfloat16* xb = xtp + (size_t)b * (PW_ * PROW_);

    stage(0, 0);
    __syncthreads();
    for (int tap = 0; tap < 9; ++tap) {
        if (tap < 8) stage(tap + 1, (tap + 1) & 1);   // loads issue early
        int ky = tap / 3, kx = tap - ky * 3;
        const __hip_bfloat16* brow =
            xb + ((h + ky) * PW_ + (w0 + ml + kx)) * C_ + kh * 128 + kq * 8;
        const __hip_bfloat16* arow = aS[tap & 1] + kh * 4096 + lane * 8;
#pragma unroll
        for (int ks = 0; ks < 4; ++ks) {
            bf16x8 bf = *(const bf16x8*)(brow + ks * 32);
            bf16x8 a0 = *(const bf16x8*)(arow + ks * 1024);
            bf16x8 a1 = *(const bf16x8*)(arow + ks * 1024 + 512);
            acc0 = __builtin_amdgcn_mfma_f32_16x16x32_bf16(a0, bf, acc0, 0, 0, 0);
            acc1 = __builtin_amdgcn_mfma_f32_16x16x32_bf16(a1, bf, acc1, 0, 0, 0);
        }
        __syncthreads();
    }

    // cross-half reduction in LDS
    if (kh == 1) {
        red[(nt * 64 + lane) * 2 + 0] = acc0;
        red[(nt * 64 + lane) * 2 + 1] = acc1;
    }
    __syncthreads();
    if (kh == 0) {
        acc0 += red[(nt * 64 + lane) * 2 + 0];
        acc1 += red[(nt * 64 + lane) * 2 + 1];
        // C/D: col=lane&15 -> w, row=kq*4+r -> out channel j
        int w = w0 + ml;
#pragma unroll
        for (int r = 0; r < 4; ++r) {
            int j0 = kq * 4 + r;
            off2[((size_t)(b * 9 + (j0 >> 1)) * HW_ + h * W_ + w) * 2 + (j0 & 1)] =
                __float2bfloat16(acc0[r] + bias[j0]);
            int j1 = 16 + kq * 4 + r;
            if (j1 < 18)
                off2[((size_t)(b * 9 + (j1 >> 1)) * HW_ + h * W_ + w) * 2 + (j1 & 1)] =
                    __float2bfloat16(acc1[r] + bias[j1]);
        }
    }
}

// ---------------------------------------------------------------------------
// deform conv via MFMA: EXACT r0/v1 structure (57.2us measured) — LDS
// double-buffered B-tile, 1 barrier/tap, sample(k+1) overlaps mmtap(k),
// 27.6KB LDS -> 5 blocks/CU. Restored verbatim after two failed pipeline
// restructures proved hipcc won't hold gather pipelines in registers:
//   v2 (gather/finish split, LB(384,6)=85 VGPR cap): spilled corners to
//     scratch, +46MB HBM, 73us.  v3 (barrier-free per-wave tiles, 128 cap):
//     compiler still chose VGPR=64 and serialized the tap chain, 97us.
// v1's measured VALUBusy 44% ~= the 22us interp-VALU floor, i.e. sampling
// math is near its limit; remaining stall is gather latency the compiler
// won't pipeline at source level. Do not restructure this kernel again.
// ---------------------------------------------------------------------------
__global__ __launch_bounds__(384, 4) void deform_kernel(
    const __hip_bfloat16* __restrict__ xtp, const __hip_bfloat16* __restrict__ off2,
    const __hip_bfloat16* __restrict__ aW, float* __restrict__ out)
{
    int blk = blockIdx.x;                 // 0..1535
    int xcd = blk & 7;
    int s   = blk >> 3;                   // 0..191
    int bg  = xcd * 2 + (s / H_);         // 0..15
    int h   = s % H_;
    int g   = bg & 3;
    int b   = bg >> 2;
    int t    = threadIdx.x;
    int lane = t & 63;
    int wave = __builtin_amdgcn_readfirstlane(t >> 6);  // 0..5
    int half   = wave & 1;                // co half (32)
    int wthird = wave >> 1;               // w third (32)

    __shared__ __align__(16) __hip_bfloat16 sS[2][96 * 72]; // [w][64c+pad]

    // interior origin: padded (1,1) == image (0,0)
    const __hip_bfloat16* xb =
        xtp + ((size_t)b * (PW_ * PW_) + PW_ + 1) * C_ + g * CG_;
    const __hip_bfloat162* offp =
        (const __hip_bfloat162*)off2 + (size_t)(b * 9) * HW_ + h * W_;
    const __hip_bfloat16* aWg = aW + (g * 9) * 4096;

    int tw8 = t >> 3;                     // 0..47
    int j8  = (t & 7) * 8;                // c offset within group

    f32x4 acc[2][2] = {};                 // [ct co16][wt w16]

    auto sample = [&](int k, int p) {
        int ky = k / 3, kx = k - ky * 3;
#pragma unroll
        for (int it = 0; it < 2; ++it) {
            int w  = it * 48 + tw8;
            __hip_bfloat162 pr = offp[k * HW_ + w];
            float py = (float)(h + ky - 1) + __bfloat162float(pr.x);
            float px = (float)(w + kx - 1) + __bfloat162float(pr.y);
            bool valid = (py > -1.f) && (py < (float)H_) &&
                         (px > -1.f) && (px < (float)W_);
            float y0f = floorf(py), x0f = floorf(px);
            float ly = py - y0f, lx = px - x0f;
            int y0 = (int)y0f, x0 = (int)x0f;
            // valid => y0,x0 in [-1,95]; all 4 corners inside padded image.
            // invalid => base -> padded (0,0) halo corner, weights zeroed.
            int base = valid ? (y0 * PW_ + x0) * C_ : -(PW_ + 1) * C_;
            float wy1 = valid ? ly : 0.f;
            float wy0 = valid ? (1.f - ly) : 0.f;
            float mx0 = 1.f - lx;
            float bw00 = wy0 * mx0, bw01 = wy0 * lx;
            float bw10 = wy1 * mx0, bw11 = wy1 * lx;
            const __hip_bfloat16* p0 = xb + base + j8;
            bf16x8 c00 = *(const bf16x8*)(p0);
            bf16x8 c01 = *(const bf16x8*)(p0 + C_);
            bf16x8 c10 = *(const bf16x8*)(p0 + PROW_);
            bf16x8 c11 = *(const bf16x8*)(p0 + PROW_ + C_);
            bf16x8 r;
#pragma unroll
            for (int e = 0; e < 8; ++e) {
                float v = bw00 * (float)c00[e] + bw01 * (float)c01[e]
                        + bw10 * (float)c10[e] + bw11 * (float)c11[e];
                r[e] = (__bf16)v;
            }
            *(bf16x8*)(&sS[p][w * 72 + j8]) = r;
        }
    };

    auto mmtap = [&](int k, int p) {
        bf16x8 afrag[2][2];               // [ks][ct]
        const __hip_bfloat16* at = aWg + k * 4096 + half * 1024 + lane * 8;
#pragma unroll
        for (int ks = 0; ks < 2; ++ks)
#pragma unroll
            for (int ct = 0; ct < 2; ++ct)
                afrag[ks][ct] = *(const bf16x8*)(at + ks * 2048 + ct * 512);
#pragma unroll
        for (int ks = 0; ks < 2; ++ks) {
#pragma unroll
            for (int wt = 0; wt < 2; ++wt) {
                int wrow = wthird * 32 + wt * 16 + (lane & 15);
                bf16x8 bfrag = *(const bf16x8*)(
                    &sS[p][wrow * 72 + ks * 32 + (lane >> 4) * 8]);
                acc[0][wt] = __builtin_amdgcn_mfma_f32_16x16x32_bf16(
                                 afrag[ks][0], bfrag, acc[0][wt], 0, 0, 0);
                acc[1][wt] = __builtin_amdgcn_mfma_f32_16x16x32_bf16(
                                 afrag[ks][1], bfrag, acc[1][wt], 0, 0, 0);
            }
        }
    };

    sample(0, 0);
    __syncthreads();
    for (int k = 0; k < K_; ++k) {
        if (k < K_ - 1) sample(k + 1, (k + 1) & 1);  // loads issue early
        mmtap(k, k & 1);
        __syncthreads();
    }

    // epilogue: C/D layout col=lane&15 (w), row=(lane>>4)*4+reg (co)
    float* ob = out + ((b * C_ + g * CG_ + half * 32) * HW_) + h * W_ + wthird * 32;
    int rbase = (lane >> 4) * 4;
    int ncol  = lane & 15;
#pragma unroll
    for (int ct = 0; ct < 2; ++ct)
#pragma unroll
        for (int wt = 0; wt < 2; ++wt)
#pragma unroll
            for (int r = 0; r < 4; ++r)
                __builtin_nontemporal_store(
                    acc[ct][wt][r],
                    ob + (ct * 16 + rbase + r) * HW_ + wt * 16 + ncol);
}

// ---------------------------------------------------------------------------
extern "C" void kernel_launch(void* const* d_in, const int* in_sizes, int n_in,
                              void* d_out, int out_size, void* d_ws, size_t ws_size,
                              hipStream_t stream) {
    const float* x    = (const float*)d_in[0];
    const float* ow   = (const float*)d_in[1];   // offset_w (18,256,3,3)
    const float* obi  = (const float*)d_in[2];   // offset_b (18,)
    const float* wt   = (const float*)d_in[3];   // weight   (256,64,3,3)

    // ws: xtp bf16 padded (19.67MB) | off2 bf16 (1.33MB) | aW (0.29MB) | aOW (0.15MB)
    __hip_bfloat16* xtp  = (__hip_bfloat16*)d_ws;
    __hip_bfloat16* off2 = xtp + (size_t)B_ * PW_ * PW_ * C_;
    __hip_bfloat16* aW   = off2 + (size_t)B_ * 9 * HW_ * 2;
    __hip_bfloat16* aOW  = aW + 147456;

    transpose_prep_kernel<<<B_ * H_ * 2, 256, 0, stream>>>(x, ow, wt, xtp, aOW, aW);
    offset_conv_kernel<<<B_ * H_ * 2, 384, 0, stream>>>(xtp, aOW, obi, off2);
    deform_kernel<<<B_ * G_ * H_, 384, 0, stream>>>(xtp, off2, aW, (float*)d_out);
}